// Round 2
// baseline (178.021 us; speedup 1.0000x reference)
//
#include <hip/hip_runtime.h>
#include <hip/hip_cooperative_groups.h>

namespace cg = cooperative_groups;

#define DIM 1024
#define NQ 10

// ---------- complex helpers (float2 = {re, im}) ----------
__device__ __forceinline__ float2 cmul(float2 a, float2 b) {
    return make_float2(a.x * b.x - a.y * b.y, a.x * b.y + a.y * b.x);
}
__device__ __forceinline__ float2 cadd(float2 a, float2 b) {
    return make_float2(a.x + b.x, a.y + b.y);
}
__device__ __forceinline__ float2 csub(float2 a, float2 b) {
    return make_float2(a.x - b.x, a.y - b.y);
}
__device__ __forceinline__ float2 cconj(float2 a) { return make_float2(a.x, -a.y); }

__device__ __forceinline__ void mm2(const float2* A, const float2* B, float2* C) {
    C[0] = cadd(cmul(A[0], B[0]), cmul(A[1], B[2]));
    C[1] = cadd(cmul(A[0], B[1]), cmul(A[1], B[3]));
    C[2] = cadd(cmul(A[2], B[0]), cmul(A[3], B[2]));
    C[3] = cadd(cmul(A[2], B[1]), cmul(A[3], B[3]));
}

// G[q*4..] = Rz(+w)·Ry(+w)·Rx(+w) (K1 factor). Msh[q*4..] = u2† Z u2 (q<6, sign=-1)
__device__ __forceinline__ void compute_gates(const float* __restrict__ weight,
                                              float2* G, float2* Msh, int tid) {
    if (tid < NQ) {
        int q = tid;
        const float WM = 0.632455532033676f;  // sqrt(2/5)
        float px = weight[q]      * WM * 0.5f;
        float py = weight[q + 10] * WM * 0.5f;
        float pz = weight[q + 20] * WM * 0.5f;
        float cx = cosf(px), sx = sinf(px);
        float cy = cosf(py), sy = sinf(py);
        float cz = cosf(pz), sz = sinf(pz);
        {
            float2 Rx[4] = { {cx, 0.f}, {0.f, -sx}, {0.f, -sx}, {cx, 0.f} };
            float2 Ry[4] = { {cy, 0.f}, {-sy, 0.f}, {sy, 0.f}, {cy, 0.f} };
            float2 Rz[4] = { {cz, -sz}, {0.f, 0.f}, {0.f, 0.f}, {cz, sz} };
            float2 T[4], u[4];
            mm2(Ry, Rx, T);
            mm2(Rz, T, u);
            G[q * 4 + 0] = u[0]; G[q * 4 + 1] = u[1];
            G[q * 4 + 2] = u[2]; G[q * 4 + 3] = u[3];
        }
        if (q < 6) {
            float nsx = -sx, nsy = -sy, nsz = -sz;
            float2 Rx[4] = { {cx, 0.f}, {0.f, -nsx}, {0.f, -nsx}, {cx, 0.f} };
            float2 Ry[4] = { {cy, 0.f}, {-nsy, 0.f}, {nsy, 0.f}, {cy, 0.f} };
            float2 Rz[4] = { {cz, -nsz}, {0.f, 0.f}, {0.f, 0.f}, {cz, nsz} };
            float2 T[4], u2[4];
            mm2(Ry, Rx, T);
            mm2(Rz, T, u2);
            for (int i = 0; i < 2; i++)
                for (int j = 0; j < 2; j++) {
                    float2 v = csub(cmul(cconj(u2[0 * 2 + i]), u2[0 * 2 + j]),
                                    cmul(cconj(u2[1 * 2 + i]), u2[1 * 2 + j]));
                    Msh[q * 4 + i * 2 + j] = v;
                }
        }
    }
}

// ---------- fused kernel: phase1 (z = x·K1†, transposed) | grid.sync | phase2 (K1·z + extract) ----------
// 256 blocks x 512 threads (1 block/CU, 8 waves = 2/SIMD). Cooperative launch.
// Phase 1: block = 4 rows; wave pair per row, h = c bit 9; c = h<<9 | j<<6 | lane.
//   q=1..3 register (j bits), q=4..9 shfl (lane bits), q=0 fused into the
//   LDS-transpose store (thread owns columns tid / tid+512 = q0 partners).
// Phase 2: block = 4 cols; wave pair per col, h = r bit 9; r = h<<9 | lane<<3 | j.
//   q=0 fused at load (reads both halves), q=1..6 shfl, q=7..9 register.
//   Extraction in closed form (prefix parities of lane), one atomic per block.
__global__ __launch_bounds__(512) void fused(const float* __restrict__ x,
                                             const float* __restrict__ weight,
                                             float2* __restrict__ zt,
                                             float* __restrict__ out) {
    __shared__ float2 G[40];
    __shared__ float2 Msh[24];
    __shared__ float part[8];
    __shared__ float2 sh[DIM * 5];  // transpose tile sh[c*5 + r_loc]; pitch 5 -> bounded bank alias
    int tid = threadIdx.x;
    int lane = tid & 63;
    int wv = tid >> 6;      // wave 0..7
    int h = wv & 1;

    compute_gates(weight, G, Msh, tid);
    if (blockIdx.x == 0 && tid == 0) atomicExch(out, 0.f);  // device-scope, pre-sync

    // ================= phase 1: rows =================
    {
        int rl = wv >> 1;   // row-in-block 0..3
        int r = blockIdx.x * 4 + rl;

        // coalesced scalar loads: per j, 64 lanes read 256 contiguous bytes
        const float* xp = x + r * DIM + (h << 9) + lane;
        float2 v[8];
#pragma unroll
        for (int j = 0; j < 8; j++) v[j] = make_float2(xp[j * 64], 0.f);

        __syncthreads();  // G ready

        // register stages q=1..3 (c bits 8..6 = j bits 2..0), conj gates
#pragma unroll
        for (int q = 1; q < 4; q++) {
            float2 u0 = cconj(G[q * 4]),     u1 = cconj(G[q * 4 + 1]);
            float2 u2 = cconj(G[q * 4 + 2]), u3 = cconj(G[q * 4 + 3]);
            const int hb = 1 << (3 - q);  // 4,2,1
#pragma unroll
            for (int j0 = 0; j0 < 8; j0++) {
                if ((j0 & hb) == 0) {
                    int j1 = j0 | hb;
                    float2 s0 = v[j0], s1 = v[j1];
                    v[j0] = cadd(cmul(u0, s0), cmul(u1, s1));
                    v[j1] = cadd(cmul(u2, s0), cmul(u3, s1));
                }
            }
        }
        // shfl stages q=4..9 (c bits 5..0 = lane bits 5..0)
#pragma unroll
        for (int q = 4; q < 10; q++) {
            float2 u0 = cconj(G[q * 4]),     u1 = cconj(G[q * 4 + 1]);
            float2 u2 = cconj(G[q * 4 + 2]), u3 = cconj(G[q * 4 + 3]);
            const int X = 1 << (9 - q);
            bool up = (lane & X) != 0;
            float2 go = up ? u3 : u0;
            float2 gp = up ? u2 : u1;
#pragma unroll
            for (int j = 0; j < 8; j++) {
                float2 p;
                p.x = __shfl_xor(v[j].x, X, 64);
                p.y = __shfl_xor(v[j].y, X, 64);
                v[j] = cadd(cmul(go, v[j]), cmul(gp, p));
            }
        }
        // write transpose tile
#pragma unroll
        for (int j = 0; j < 8; j++) {
            int c = (h << 9) | (j << 6) | lane;
            sh[c * 5 + rl] = v[j];
        }
        __syncthreads();
        // fused q=0 (c bit 9) + transposed store: thread owns columns cL=tid, cH=tid+512
        {
            float2 g00 = cconj(G[0]), g01 = cconj(G[1]), g10 = cconj(G[2]), g11 = cconj(G[3]);
            int cL = tid, cH = tid + 512;
            int r0 = blockIdx.x * 4;
            float2 oL[4], oH[4];
#pragma unroll
            for (int k = 0; k < 4; k++) {
                float2 L = sh[cL * 5 + k];
                float2 H = sh[cH * 5 + k];
                oL[k] = cadd(cmul(g00, L), cmul(g01, H));
                oH[k] = cadd(cmul(g10, L), cmul(g11, H));
            }
            float4* pL = (float4*)(zt + cL * DIM + r0);
            float4* pH = (float4*)(zt + cH * DIM + r0);
            pL[0] = make_float4(oL[0].x, oL[0].y, oL[1].x, oL[1].y);
            pL[1] = make_float4(oL[2].x, oL[2].y, oL[3].x, oL[3].y);
            pH[0] = make_float4(oH[0].x, oH[0].y, oH[1].x, oH[1].y);
            pH[1] = make_float4(oH[2].x, oH[2].y, oH[3].x, oH[3].y);
        }
    }

    // make zt visible across XCDs (per-XCD L2 not coherent), then grid barrier
    __threadfence();
    cg::this_grid().sync();

    // ================= phase 2: columns + extract =================
    {
        int pr = wv >> 1;   // column-in-block 0..3
        int c = blockIdx.x * 4 + pr;

        // contiguous 64 B per lane, 4 KB per wave per half: perfect coalescing
        const float4* zp = (const float4*)(zt + c * DIM);
        const float4* po = zp + h * 256 + lane * 4;          // own half (r bit9 = h)
        const float4* pp = zp + (1 - h) * 256 + lane * 4;    // partner half
        float2 a[8], b[8];
#pragma unroll
        for (int k = 0; k < 4; k++) {
            float4 t0 = po[k];
            a[2 * k]     = make_float2(t0.x, t0.y);
            a[2 * k + 1] = make_float2(t0.z, t0.w);
            float4 t1 = pp[k];
            b[2 * k]     = make_float2(t1.x, t1.y);
            b[2 * k + 1] = make_float2(t1.z, t1.w);
        }

        // q=0 (r bit 9) fused at load: new = G[h][h]*own + G[h][1-h]*partner
        float2 v[8];
        {
            float2 ga = h ? G[3] : G[0];
            float2 gb = h ? G[2] : G[1];
#pragma unroll
            for (int j = 0; j < 8; j++) v[j] = cadd(cmul(ga, a[j]), cmul(gb, b[j]));
        }
        // shfl stages q=1..6 (r bits 8..3 = lane bits 5..0)
#pragma unroll
        for (int q = 1; q < 7; q++) {
            float2 u0 = G[q * 4], u1 = G[q * 4 + 1], u2 = G[q * 4 + 2], u3 = G[q * 4 + 3];
            const int X = 1 << (6 - q);
            bool up = (lane & X) != 0;
            float2 go = up ? u3 : u0;
            float2 gp = up ? u2 : u1;
#pragma unroll
            for (int j = 0; j < 8; j++) {
                float2 p;
                p.x = __shfl_xor(v[j].x, X, 64);
                p.y = __shfl_xor(v[j].y, X, 64);
                v[j] = cadd(cmul(go, v[j]), cmul(gp, p));
            }
        }
        // register stages q=7..9 (r bits 2..0 = j bits 2..0)
#pragma unroll
        for (int q = 7; q < 10; q++) {
            float2 u0 = G[q * 4], u1 = G[q * 4 + 1], u2 = G[q * 4 + 2], u3 = G[q * 4 + 3];
            const int hb = 1 << (9 - q);  // 4,2,1
#pragma unroll
            for (int j0 = 0; j0 < 8; j0++) {
                if ((j0 & hb) == 0) {
                    int j1 = j0 | hb;
                    float2 s0 = v[j0], s1 = v[j1];
                    v[j0] = cadd(cmul(u0, s0), cmul(u1, s1));
                    v[j1] = cadd(cmul(u2, s0), cmul(u3, s1));
                }
            }
        }

        // ---- extraction: out += sum_r [pi(r)&15 == pi(c)&15] Re(M6[pi(c)>>4, pi(r)>>4] w[r,c])
        int af = c;
        af ^= af >> 1; af ^= af >> 2; af ^= af >> 4; af ^= af >> 8;  // pi(c)
        int t = af & 15;
        int a05 = af >> 4;
        // prefix parities of lane: pk = parity(lane >> k)
        int p5 = (lane >> 5) & 1;
        int p4 = p5 ^ ((lane >> 4) & 1);
        int p3 = p4 ^ ((lane >> 3) & 1);
        int p2 = p3 ^ ((lane >> 2) & 1);
        int p1 = p2 ^ ((lane >> 1) & 1);
        int p0 = p1 ^ (lane & 1);
        int t3 = (t >> 3) & 1, t2 = (t >> 2) & 1, t1b = (t >> 1) & 1, t0 = t & 1;
        bool sel = ((h ^ p0) == t3);                                    // delta on pi(r) bit 3
        int jsel = ((t2 ^ t3) << 2) | ((t1b ^ t2) << 1) | (t0 ^ t1b);   // wave-uniform
        float2 vs = v[0];
#pragma unroll
        for (int j = 1; j < 8; j++) if (jsel == j) vs = v[j];  // cndmask chain, stays in regs
        // b05 bits (pi(r) bits 9..4) = h ^ {0, p5, p4, p3, p2, p1}
        float2 m6 = make_float2(1.f, 0.f);
        int ib0 = h, ib1 = h ^ p5, ib2 = h ^ p4, ib3 = h ^ p3, ib4 = h ^ p2, ib5 = h ^ p1;
        m6 = cmul(m6, Msh[0 * 4 + ((a05 >> 5) & 1) * 2 + ib0]);
        m6 = cmul(m6, Msh[1 * 4 + ((a05 >> 4) & 1) * 2 + ib1]);
        m6 = cmul(m6, Msh[2 * 4 + ((a05 >> 3) & 1) * 2 + ib2]);
        m6 = cmul(m6, Msh[3 * 4 + ((a05 >> 2) & 1) * 2 + ib3]);
        m6 = cmul(m6, Msh[4 * 4 + ((a05 >> 1) & 1) * 2 + ib4]);
        m6 = cmul(m6, Msh[5 * 4 + (a05 & 1) * 2 + ib5]);

        float acc = sel ? (m6.x * vs.x - m6.y * vs.y) : 0.f;
#pragma unroll
        for (int off = 32; off > 0; off >>= 1) acc += __shfl_xor(acc, off, 64);
        if (lane == 0) part[wv] = acc;
        __syncthreads();
        if (tid == 0) {
            float s = part[0] + part[1] + part[2] + part[3] +
                      part[4] + part[5] + part[6] + part[7];
            atomicAdd(out, s);
        }
    }
}

extern "C" void kernel_launch(void* const* d_in, const int* in_sizes, int n_in,
                              void* d_out, int out_size, void* d_ws, size_t ws_size,
                              hipStream_t stream) {
    const float* x = (const float*)d_in[0];       // 1024*1024 fp32
    const float* weight = (const float*)d_in[1];  // 30 fp32
    float* out = (float*)d_out;                   // 1 fp32

    float2* zt = (float2*)d_ws + 8192;  // zt[c][r], 8 MB, 64 KB offset

    void* args[] = { (void*)&x, (void*)&weight, (void*)&zt, (void*)&out };
    hipLaunchCooperativeKernel((const void*)fused, dim3(256), dim3(512), args, 0, stream);
}

// Round 3
// 69.180 us; speedup vs baseline: 2.5733x; 2.5733x over previous
//
#include <hip/hip_runtime.h>

#define DIM 1024
#define NQ 10

// ---------- complex helpers (float2 = {re, im}) ----------
__device__ __forceinline__ float2 cmul(float2 a, float2 b) {
    return make_float2(a.x * b.x - a.y * b.y, a.x * b.y + a.y * b.x);
}
__device__ __forceinline__ float2 cadd(float2 a, float2 b) {
    return make_float2(a.x + b.x, a.y + b.y);
}
__device__ __forceinline__ float2 csub(float2 a, float2 b) {
    return make_float2(a.x - b.x, a.y - b.y);
}
__device__ __forceinline__ float2 cconj(float2 a) { return make_float2(a.x, -a.y); }

__device__ __forceinline__ float2 shflx2(float2 v, int X) {
    return make_float2(__shfl_xor(v.x, X, 64), __shfl_xor(v.y, X, 64));
}
__device__ __forceinline__ float2 shfl2(float2 v, int sl) {
    return make_float2(__shfl(v.x, sl, 64), __shfl(v.y, sl, 64));
}

__device__ __forceinline__ void mm2(const float2* A, const float2* B, float2* C) {
    C[0] = cadd(cmul(A[0], B[0]), cmul(A[1], B[2]));
    C[1] = cadd(cmul(A[0], B[1]), cmul(A[1], B[3]));
    C[2] = cadd(cmul(A[2], B[0]), cmul(A[3], B[2]));
    C[3] = cadd(cmul(A[2], B[1]), cmul(A[3], B[3]));
}

// G[q*4 + a*2 + b] = (Rz·Ry·Rx)(+w)[a][b]  (K1 factor, row-major)
// Msh[q*4 + a*2 + b] = (u2† Z u2)[a][b] for q<6 (sign=-1 gates)
__device__ __forceinline__ void compute_gates(const float* __restrict__ weight,
                                              float2* G, float2* Msh, int tid) {
    if (tid < NQ) {
        int q = tid;
        const float WM = 0.632455532033676f;  // sqrt(2/5)
        float px = weight[q]      * WM * 0.5f;
        float py = weight[q + 10] * WM * 0.5f;
        float pz = weight[q + 20] * WM * 0.5f;
        float cx = cosf(px), sx = sinf(px);
        float cy = cosf(py), sy = sinf(py);
        float cz = cosf(pz), sz = sinf(pz);
        {
            float2 Rx[4] = { {cx, 0.f}, {0.f, -sx}, {0.f, -sx}, {cx, 0.f} };
            float2 Ry[4] = { {cy, 0.f}, {-sy, 0.f}, {sy, 0.f}, {cy, 0.f} };
            float2 Rz[4] = { {cz, -sz}, {0.f, 0.f}, {0.f, 0.f}, {cz, sz} };
            float2 T[4], u[4];
            mm2(Ry, Rx, T);
            mm2(Rz, T, u);
            G[q * 4 + 0] = u[0]; G[q * 4 + 1] = u[1];
            G[q * 4 + 2] = u[2]; G[q * 4 + 3] = u[3];
        }
        if (q < 6) {
            float nsx = -sx, nsy = -sy, nsz = -sz;
            float2 Rx[4] = { {cx, 0.f}, {0.f, -nsx}, {0.f, -nsx}, {cx, 0.f} };
            float2 Ry[4] = { {cy, 0.f}, {-nsy, 0.f}, {nsy, 0.f}, {cy, 0.f} };
            float2 Rz[4] = { {cz, -nsz}, {0.f, 0.f}, {0.f, 0.f}, {cz, nsz} };
            float2 T[4], u2[4];
            mm2(Ry, Rx, T);
            mm2(Rz, T, u2);
            for (int i = 0; i < 2; i++)
                for (int j = 0; j < 2; j++) {
                    float2 v = csub(cmul(cconj(u2[0 * 2 + i]), u2[0 * 2 + j]),
                                    cmul(cconj(u2[1 * 2 + i]), u2[1 * 2 + j]));
                    Msh[q * 4 + i * 2 + j] = v;
                }
        }
    }
}

__global__ void zero_out(float* out) { out[0] = 0.f; }

// ---------- single-pass kernel: out = sum_i <x[i,:], Re t_i> ----------
// t_i = K1† · Π† · (M6 ⊗ I16) · f_i, with f_i[rho] = K1[L^-1 rho, i] separable
// (L = prefix-xor "pi", L^-1 = Gray encode; d = rho ^ (rho>>1) gives the gate
// row-select bits). Element layout: e = h<<9 | r<<6 | lane, wave pair per row
// (h = wave&1). pi fixes bit 9, so the permutation Π† (s'[c] = s[pi(c)]) stays
// inside the wave: static register bijection + one computed-source shfl.
// Cross-wave stages (bit 9: M6 q=0 and K1† q=0) via two LDS exchanges.
__global__ __launch_bounds__(256) void qulinear(const float* __restrict__ x,
                                                const float* __restrict__ weight,
                                                float* __restrict__ out) {
    __shared__ float2 G[40];
    __shared__ float2 Msh[24];
    __shared__ float2 ex[4 * 8 * 64];  // [wave][reg][lane], 16 KB
    __shared__ float part[4];
    int tid = threadIdx.x;
    int lane = tid & 63;
    int wv = tid >> 6;                  // 0..3
    int h = wv & 1;                     // element bit 9
    int i = blockIdx.x * 2 + (wv >> 1); // row

    // early coalesced x loads: j = h<<9 | r<<6 | lane
    const float* xp = x + i * DIM + (h << 9) + lane;
    float xv[8];
#pragma unroll
    for (int r = 0; r < 8; r++) xv[r] = xp[r << 6];

    compute_gates(weight, G, Msh, tid);
    __syncthreads();

    // ---- build f[rho], rho = h<<9 | r<<6 | lane; d = rho ^ (rho>>1)
    int i9=(i>>9)&1, i8=(i>>8)&1, i7=(i>>7)&1, i6=(i>>6)&1, i5=(i>>5)&1;
    int i4=(i>>4)&1, i3=(i>>3)&1, i2=(i>>2)&1, i1=(i>>1)&1, i0=i&1;
    int dl = lane ^ (lane >> 1);        // bits 4..0 = d4..d0
    int l5 = (lane >> 5) & 1;
    // lane-common chain: qubits 5..9 (rows d4..d0, cols i4..i0)
    float2 Cl = cmul(G[20 + ((dl>>4)&1)*2 + i4],
               cmul(G[24 + ((dl>>3)&1)*2 + i3],
               cmul(G[28 + ((dl>>2)&1)*2 + i2],
               cmul(G[32 + ((dl>>1)&1)*2 + i1],
                    G[36 + ((dl    )&1)*2 + i0]))));
    // qubit 4: row d5 = l5 ^ r0
    float2 CA = cmul(Cl, G[16 + l5 * 2 + i5]);        // r0 = 0
    float2 CB = cmul(Cl, G[16 + (1 - l5) * 2 + i5]);  // r0 = 1
    // lane-uniform per-reg prefix: qubits 0..3 (rows h, h^r2, r2^r1, r1^r0)
    float2 e0    = G[0 + h * 2 + i9];
    float2 m01_0 = cmul(e0, G[4 + (h ^ 0) * 2 + i8]);
    float2 m01_1 = cmul(e0, G[4 + (h ^ 1) * 2 + i8]);
    float2 m23_00 = cmul(G[8 + 0 + i7], G[12 + 0 + i6]);
    float2 m23_01 = cmul(G[8 + 0 + i7], G[12 + 2 + i6]);
    float2 m23_10 = cmul(G[8 + 2 + i7], G[12 + 0 + i6]);
    float2 m23_11 = cmul(G[8 + 2 + i7], G[12 + 2 + i6]);
    float2 v[8];
    v[0] = cmul(cmul(m01_0, m23_00), CA);  // r=000: x=r2^r1=0, y=r1^r0=0
    v[1] = cmul(cmul(m01_0, m23_01), CB);  // 001: x=0,y=1
    v[2] = cmul(cmul(m01_0, m23_11), CA);  // 010: x=1,y=1
    v[3] = cmul(cmul(m01_0, m23_10), CB);  // 011: x=1,y=0
    v[4] = cmul(cmul(m01_1, m23_10), CA);  // 100: x=1,y=0
    v[5] = cmul(cmul(m01_1, m23_11), CB);  // 101: x=1,y=1
    v[6] = cmul(cmul(m01_1, m23_01), CA);  // 110: x=0,y=1
    v[7] = cmul(cmul(m01_1, m23_00), CB);  // 111: x=0,y=0

    // ---- M6 stage q=0 (bit 9) via LDS exchange
#pragma unroll
    for (int r = 0; r < 8; r++) ex[(wv * 8 + r) * 64 + lane] = v[r];
    __syncthreads();
    {
        float2 Ma = Msh[h * 2 + h];        // m0[h][h]
        float2 Mb = Msh[h * 2 + 1 - h];    // m0[h][1-h]
        int pw = wv ^ 1;
#pragma unroll
        for (int r = 0; r < 8; r++) {
            float2 p = ex[(pw * 8 + r) * 64 + lane];
            v[r] = cadd(cmul(Ma, v[r]), cmul(Mb, p));
        }
    }
    // ---- M6 q=1..3: register bits r2,r1,r0 (pairs 4,2,1)
#pragma unroll
    for (int q = 1; q < 4; q++) {
        float2 m00 = Msh[q*4], m01 = Msh[q*4+1], m10 = Msh[q*4+2], m11 = Msh[q*4+3];
        const int hb = 8 >> q;
#pragma unroll
        for (int j0 = 0; j0 < 8; j0++) {
            if ((j0 & hb) == 0) {
                int j1 = j0 | hb;
                float2 s0 = v[j0], s1 = v[j1];
                v[j0] = cadd(cmul(m00, s0), cmul(m01, s1));
                v[j1] = cadd(cmul(m10, s0), cmul(m11, s1));
            }
        }
    }
    // ---- M6 q=4,5: lane bits 5,4 (shfl_xor 32,16)
#pragma unroll
    for (int q = 4; q < 6; q++) {
        const int X = 1 << (9 - q);
        bool up = (lane & X) != 0;
        float2 go = up ? Msh[q*4+3] : Msh[q*4+0];
        float2 gp = up ? Msh[q*4+2] : Msh[q*4+1];
#pragma unroll
        for (int r = 0; r < 8; r++) {
            float2 p = shflx2(v[r], X);
            v[r] = cadd(cmul(go, v[r]), cmul(gp, p));
        }
    }

    // ---- permutation: s'[h,r,l] = s[h, pi3(r)^(h?7:0), pi6(l)^(flip?63:0)]
    int pl6 = lane ^ (lane >> 1); pl6 ^= pl6 >> 2; pl6 ^= pl6 >> 4; pl6 &= 63;
    float2 t2[8];
    if (h == 0) {
        t2[0] = shfl2(v[0], pl6);       // r=0: R=0, flip=0
        t2[1] = shfl2(v[1], pl6 ^ 63);  // r=1: R=1, flip=1
        t2[2] = shfl2(v[3], pl6 ^ 63);  // r=2: R=3, flip=1
        t2[3] = shfl2(v[2], pl6);       // r=3: R=2, flip=0
        t2[4] = shfl2(v[7], pl6 ^ 63);  // r=4: R=7, flip=1
        t2[5] = shfl2(v[6], pl6);       // r=5: R=6, flip=0
        t2[6] = shfl2(v[4], pl6);       // r=6: R=4, flip=0
        t2[7] = shfl2(v[5], pl6 ^ 63);  // r=7: R=5, flip=1
    } else {
        t2[0] = shfl2(v[7], pl6 ^ 63);
        t2[1] = shfl2(v[6], pl6);
        t2[2] = shfl2(v[4], pl6);
        t2[3] = shfl2(v[5], pl6 ^ 63);
        t2[4] = shfl2(v[0], pl6);
        t2[5] = shfl2(v[1], pl6 ^ 63);
        t2[6] = shfl2(v[3], pl6 ^ 63);
        t2[7] = shfl2(v[2], pl6);
    }
#pragma unroll
    for (int r = 0; r < 8; r++) v[r] = t2[r];

    // ---- K1† stage q=0 (bit 9) via LDS exchange #2
    __syncthreads();  // all exchange-1 reads done
#pragma unroll
    for (int r = 0; r < 8; r++) ex[(wv * 8 + r) * 64 + lane] = v[r];
    __syncthreads();
    {
        float2 ga = cconj(h ? G[3] : G[0]);  // conj(u[h][h])
        float2 gb = cconj(h ? G[1] : G[2]);  // conj(u[1-h][h])
        int pw = wv ^ 1;
#pragma unroll
        for (int r = 0; r < 8; r++) {
            float2 p = ex[(pw * 8 + r) * 64 + lane];
            v[r] = cadd(cmul(ga, v[r]), cmul(gb, p));
        }
    }
    // ---- K1† q=1..3: register bits (dagger: new0 = conj(u00)s0 + conj(u10)s1)
#pragma unroll
    for (int q = 1; q < 4; q++) {
        float2 c00 = cconj(G[q*4]),     c10 = cconj(G[q*4+2]);
        float2 c01 = cconj(G[q*4+1]),   c11 = cconj(G[q*4+3]);
        const int hb = 8 >> q;
#pragma unroll
        for (int j0 = 0; j0 < 8; j0++) {
            if ((j0 & hb) == 0) {
                int j1 = j0 | hb;
                float2 s0 = v[j0], s1 = v[j1];
                v[j0] = cadd(cmul(c00, s0), cmul(c10, s1));
                v[j1] = cadd(cmul(c01, s0), cmul(c11, s1));
            }
        }
    }
    // ---- K1† q=4..9: lane bits 5..0 (shfl_xor 32..1)
#pragma unroll
    for (int q = 4; q < 10; q++) {
        const int X = 1 << (9 - q);
        bool up = (lane & X) != 0;
        float2 go = cconj(up ? G[q*4+3] : G[q*4+0]);
        float2 gp = cconj(up ? G[q*4+1] : G[q*4+2]);
#pragma unroll
        for (int r = 0; r < 8; r++) {
            float2 p = shflx2(v[r], X);
            v[r] = cadd(cmul(go, v[r]), cmul(gp, p));
        }
    }

    // ---- dot with x row (real) against Re(t), reduce, accumulate
    float acc = 0.f;
#pragma unroll
    for (int r = 0; r < 8; r++) acc += xv[r] * v[r].x;
#pragma unroll
    for (int off = 32; off > 0; off >>= 1) acc += __shfl_xor(acc, off, 64);
    if (lane == 0) part[wv] = acc;
    __syncthreads();
    if (tid == 0) atomicAdd(out, part[0] + part[1] + part[2] + part[3]);
}

extern "C" void kernel_launch(void* const* d_in, const int* in_sizes, int n_in,
                              void* d_out, int out_size, void* d_ws, size_t ws_size,
                              hipStream_t stream) {
    const float* x = (const float*)d_in[0];       // 1024*1024 fp32
    const float* weight = (const float*)d_in[1];  // 30 fp32
    float* out = (float*)d_out;                   // 1 fp32

    zero_out<<<1, 1, 0, stream>>>(out);           // ordered before qulinear's atomics
    qulinear<<<512, 256, 0, stream>>>(x, weight, out);
}